// Round 2
// baseline (250.773 us; speedup 1.0000x reference)
//
#include <hip/hip_runtime.h>

// AR(24) rollout, closed form. The recursion y_t = W·window + b is linear, so
// y_t = sum_k C[t][k]*x_k + beta_t with (C,beta) independent of (b,d).
// Kernel 1 computes C[168][25] once (tiny, serial); kernel 2 applies it as a
// massively parallel rank-24 contraction (memory-bound streaming).
//
// Round-0 lesson: per-thread arrays indexed by loop vars ((j+k)%24) landed in
// scratch (~142 cyc/access). All hot state here is NAMED SCALARS via macros.

#define BATCH 256
#define SEQ   336
#define DIMS  512
#define ORDER 24
#define TSEQ  168
#define CSTRIDE 64   // floats per C row in d_ws (256 B, float4-aligned)
#define NTILE 4
#define TTILE 42     // 168 / 4

#define REP24(M) M(0) M(1) M(2) M(3) M(4) M(5) M(6) M(7) M(8) M(9) M(10) M(11) \
                 M(12) M(13) M(14) M(15) M(16) M(17) M(18) M(19) M(20) M(21) M(22) M(23)

// ---------------------------------------------------------------------------
// Kernel 1: coefficient recursion. 1 block, 1 wave. Lane c (< 24) tracks the
// coefficient of initial-window element c; lane 24 tracks the bias term
// (window components start at 0, +b injected every step). Lanes >= 25 compute
// zeros into the row padding. Window shift = pure register renaming (full
// unroll of all 168 steps).
// ---------------------------------------------------------------------------
__global__ __launch_bounds__(64) void ar_coeff_kernel(
    const float* __restrict__ W, const float* __restrict__ bias,
    float* __restrict__ C)
{
    const int lane = threadIdx.x;
#define DECLW(j) const float cw##j = W[j];
    REP24(DECLW)
#undef DECLW
    const float badd = (lane == ORDER) ? bias[0] : 0.0f;
#define DECLS(j) float s##j = (lane == (j)) ? 1.0f : 0.0f;
    REP24(DECLS)
#undef DECLS

    float* cp = C + lane;
#pragma unroll
    for (int t = 0; t < TSEQ; ++t) {
        float a0 = fmaf(cw0,  s0,  badd);
        float a1 = cw1  * s1;
        float a2 = cw2  * s2;
        float a3 = cw3  * s3;
        a0 = fmaf(cw4,  s4,  a0);  a1 = fmaf(cw5,  s5,  a1);
        a2 = fmaf(cw6,  s6,  a2);  a3 = fmaf(cw7,  s7,  a3);
        a0 = fmaf(cw8,  s8,  a0);  a1 = fmaf(cw9,  s9,  a1);
        a2 = fmaf(cw10, s10, a2);  a3 = fmaf(cw11, s11, a3);
        a0 = fmaf(cw12, s12, a0);  a1 = fmaf(cw13, s13, a1);
        a2 = fmaf(cw14, s14, a2);  a3 = fmaf(cw15, s15, a3);
        a0 = fmaf(cw16, s16, a0);  a1 = fmaf(cw17, s17, a1);
        a2 = fmaf(cw18, s18, a2);  a3 = fmaf(cw19, s19, a3);
        a0 = fmaf(cw20, s20, a0);  a1 = fmaf(cw21, s21, a1);
        a2 = fmaf(cw22, s22, a2);  a3 = fmaf(cw23, s23, a3);
        const float y = (a0 + a1) + (a2 + a3);
        cp[t * CSTRIDE] = y;   // all 64 lanes write; lanes 25..63 write zeros into pad
        s0 = s1;  s1 = s2;  s2 = s3;  s3 = s4;  s4 = s5;  s5 = s6;
        s6 = s7;  s7 = s8;  s8 = s9;  s9 = s10; s10 = s11; s11 = s12;
        s12 = s13; s13 = s14; s14 = s15; s15 = s16; s16 = s17; s17 = s18;
        s18 = s19; s19 = s20; s20 = s21; s21 = s22; s22 = s23; s23 = y;
    }
}

// ---------------------------------------------------------------------------
// Kernel 2: out[b,t,d] = dot(C[t,0:24], x[b, 312+k, d]) + beta_t.
// Block = (b, t-tile of 42). 256 threads, each owns 2 consecutive d's
// (float2 loads/stores -> 512 B per wave access). Window in 48 named-scalar
// VGPRs; 4 independent FMA chains (ax/ay/bx/by) for ILP.
// ---------------------------------------------------------------------------
__global__ __launch_bounds__(256, 4) void ar_apply_kernel(
    const float* __restrict__ x, const float* __restrict__ C,
    float* __restrict__ out)
{
    const int b    = blockIdx.x >> 2;
    const int tile = blockIdx.x & (NTILE - 1);

    // Window load: x[b, SEQ-ORDER+j, d0..d0+1], consecutive lanes consecutive d.
    const float2* xp =
        (const float2*)(x + ((size_t)b * SEQ + (SEQ - ORDER)) * DIMS) + threadIdx.x;
#define LOADW(j) const float2 w##j = xp[(j) * (DIMS / 2)];
    REP24(LOADW)
#undef LOADW

    float2* op = (float2*)(out + ((size_t)b * TSEQ + tile * TTILE) * DIMS) + threadIdx.x;
    const float* crow = C + (size_t)(tile * TTILE) * CSTRIDE;

#pragma unroll 2
    for (int i = 0; i < TTILE; ++i) {
        const float4 c0 = *(const float4*)(crow + 0);
        const float4 c1 = *(const float4*)(crow + 4);
        const float4 c2 = *(const float4*)(crow + 8);
        const float4 c3 = *(const float4*)(crow + 12);
        const float4 c4 = *(const float4*)(crow + 16);
        const float4 c5 = *(const float4*)(crow + 20);
        const float beta = crow[24];

        float ax = beta, ay = beta, bx = 0.0f, by = 0.0f;
#define FMA2(cc, j) ax = fmaf(cc, w##j.x, ax); ay = fmaf(cc, w##j.y, ay);
#define FMB2(cc, j) bx = fmaf(cc, w##j.x, bx); by = fmaf(cc, w##j.y, by);
        FMA2(c0.x, 0)  FMB2(c0.y, 1)  FMA2(c0.z, 2)  FMB2(c0.w, 3)
        FMA2(c1.x, 4)  FMB2(c1.y, 5)  FMA2(c1.z, 6)  FMB2(c1.w, 7)
        FMA2(c2.x, 8)  FMB2(c2.y, 9)  FMA2(c2.z, 10) FMB2(c2.w, 11)
        FMA2(c3.x, 12) FMB2(c3.y, 13) FMA2(c3.z, 14) FMB2(c3.w, 15)
        FMA2(c4.x, 16) FMB2(c4.y, 17) FMA2(c4.z, 18) FMB2(c4.w, 19)
        FMA2(c5.x, 20) FMB2(c5.y, 21) FMA2(c5.z, 22) FMB2(c5.w, 23)
#undef FMA2
#undef FMB2

        *op = make_float2(ax + bx, ay + by);
        op += DIMS / 2;        // next t
        crow += CSTRIDE;
    }
}

extern "C" void kernel_launch(void* const* d_in, const int* in_sizes, int n_in,
                              void* d_out, int out_size, void* d_ws, size_t ws_size,
                              hipStream_t stream) {
    const float* x    = (const float*)d_in[0];
    const float* W    = (const float*)d_in[1];
    const float* bias = (const float*)d_in[2];
    float* out = (float*)d_out;
    float* C   = (float*)d_ws;   // needs TSEQ*CSTRIDE*4 = 43 KB

    ar_coeff_kernel<<<1, 64, 0, stream>>>(W, bias, C);
    ar_apply_kernel<<<BATCH * NTILE, 256, 0, stream>>>(x, C, out);
}

// Round 3
// 238.171 us; speedup vs baseline: 1.0529x; 1.0529x over previous
//
#include <hip/hip_runtime.h>

// AR(24) rollout: out[b,t,d], t in [0,168), from last 24 timesteps of x[b,:,d].
// One thread per (b,d) scalar sequence; window in 24 registers. Time loop
// unrolled in groups of ORDER so the sliding window is static register
// rotation (constant-folded (j+k)%24 indices; verified register-resident in
// R0 — kernel ran ~23 us, i.e. at the HBM write floor).
//
// R2 lesson: dur_us includes ~216 us of harness 0xAA fills; the two-kernel
// closed-form variant only added a serialized launch (+11.5 us). Single
// kernel is optimal. Only delta vs R0: non-temporal stores for the 88 MB
// streaming output (never re-read).

#define BATCH 256
#define SEQ   336
#define DIMS  512
#define ORDER 24
#define TSEQ  168

__global__ __launch_bounds__(256) void ar_rollout_kernel(
    const float* __restrict__ x,     // [BATCH, SEQ, DIMS]
    const float* __restrict__ W,     // [ORDER, 1]
    const float* __restrict__ bias,  // [1]
    float* __restrict__ out)         // [BATCH, TSEQ, DIMS]
{
    const int tid = blockIdx.x * blockDim.x + threadIdx.x;  // b*DIMS + d
    const int d = tid & (DIMS - 1);
    const int b = tid >> 9;          // tid / DIMS
    if (b >= BATCH) return;

    // AR coefficients (wave-uniform -> scalar broadcasts) and bias.
    float wc[ORDER];
#pragma unroll
    for (int k = 0; k < ORDER; ++k) wc[k] = W[k];
    const float bb = bias[0];

    // Init window: x[b, SEQ-ORDER+k, d], k = 0..23 (oldest first).
    // Consecutive lanes = consecutive d -> each of the 24 loads is coalesced.
    const float* xp = x + ((size_t)b * SEQ + (SEQ - ORDER)) * DIMS + d;
    float w[ORDER];
#pragma unroll
    for (int k = 0; k < ORDER; ++k) w[k] = xp[(size_t)k * DIMS];

    // Rollout. At step j within a group, logical window element k lives in
    // physical register w[(j+k) % ORDER]; the new value overwrites w[j].
    // Serial FMA chain kept identical to R0 (absmax 0.0); compute is 6.7 us
    // issue-bound vs 15.5 us memory floor, so chain latency is hidden.
    float* op = out + (size_t)b * TSEQ * DIMS + d;
#pragma unroll 1
    for (int g = 0; g < TSEQ / ORDER; ++g) {
#pragma unroll
        for (int j = 0; j < ORDER; ++j) {
            float y = bb;
#pragma unroll
            for (int k = 0; k < ORDER; ++k)
                y = fmaf(w[(j + k) % ORDER], wc[k], y);
            w[j] = y;
            __builtin_nontemporal_store(y, op);  // streaming 88 MB, never re-read
            op += DIMS;
        }
    }
}

extern "C" void kernel_launch(void* const* d_in, const int* in_sizes, int n_in,
                              void* d_out, int out_size, void* d_ws, size_t ws_size,
                              hipStream_t stream) {
    const float* x    = (const float*)d_in[0];
    const float* W    = (const float*)d_in[1];
    const float* bias = (const float*)d_in[2];
    // d_in[3] is tar_seq_len (==168), compile-time constant here.
    float* out = (float*)d_out;

    const int threads = 256;
    const int blocks  = (BATCH * DIMS) / threads;  // 512
    ar_rollout_kernel<<<blocks, threads, 0, stream>>>(x, W, bias, out);
}